// Round 7
// baseline (334.368 us; speedup 1.0000x reference)
//
#include <hip/hip_runtime.h>

#define N_NODES 100000
#define N_EDGES 600000
#define N_GRAPHS 64

// ---------------- CSR build ----------------

__global__ void k_count(const int* __restrict__ dst, int* __restrict__ deg) {
    int e = blockIdx.x * 256 + threadIdx.x;
    if (e < N_EDGES) atomicAdd(&deg[dst[e]], 1);
}

__global__ void k_scan1(const int* __restrict__ deg, int* __restrict__ offs,
                        int* __restrict__ bsums) {
    __shared__ int s[256];
    int t = threadIdx.x, b = blockIdx.x;
    int base = b * 1024 + t * 4;
    int v0 = (base + 0 < N_NODES) ? deg[base + 0] : 0;
    int v1 = (base + 1 < N_NODES) ? deg[base + 1] : 0;
    int v2 = (base + 2 < N_NODES) ? deg[base + 2] : 0;
    int v3 = (base + 3 < N_NODES) ? deg[base + 3] : 0;
    int tsum = v0 + v1 + v2 + v3;
    s[t] = tsum;
    __syncthreads();
    for (int o = 1; o < 256; o <<= 1) {
        int x = (t >= o) ? s[t - o] : 0;
        __syncthreads();
        s[t] += x;
        __syncthreads();
    }
    int p = s[t] - tsum;
    if (base + 0 < N_NODES) offs[base + 0] = p;
    p += v0;
    if (base + 1 < N_NODES) offs[base + 1] = p;
    p += v1;
    if (base + 2 < N_NODES) offs[base + 2] = p;
    p += v2;
    if (base + 3 < N_NODES) offs[base + 3] = p;
    if (t == 255) bsums[b] = s[255];
}

__global__ void k_scan2(const int* __restrict__ bsums, int* __restrict__ boff) {
    __shared__ int s[128];
    int t = threadIdx.x;
    int nb = (N_NODES + 1023) / 1024;
    int v = (t < nb) ? bsums[t] : 0;
    s[t] = v;
    __syncthreads();
    for (int o = 1; o < 128; o <<= 1) {
        int x = (t >= o) ? s[t - o] : 0;
        __syncthreads();
        s[t] += x;
        __syncthreads();
    }
    boff[t] = s[t] - v;
}

__global__ void k_scan3(int* __restrict__ offs, const int* __restrict__ boff,
                        int* __restrict__ cursor) {
    int i = blockIdx.x * 256 + threadIdx.x;
    if (i < N_NODES) {
        int v = offs[i] + boff[i >> 10];
        offs[i] = v;
        cursor[i] = v;
    }
}

__global__ void k_fill(const int* __restrict__ src, const int* __restrict__ dst,
                       int* __restrict__ cursor, int* __restrict__ ssrc) {
    int e = blockIdx.x * 256 + threadIdx.x;
    if (e < N_EDGES) {
        int d = dst[e];
        int pos = atomicAdd(&cursor[d], 1);
        ssrc[pos] = src[e];
    }
}

// ---------------- weight prepack ----------------
// Pg[k*128 + d]: d<64 -> W1l[d][k], d>=64 -> W1r[d-64][k]   (xform1 B matrix)
// P2g[k*32 + d]: d<16 -> W2l[d][k], d>=16 -> W2r[d-16][k]   (xform2, s_load rows)
__global__ void k_prepack(const float* __restrict__ W1l, const float* __restrict__ W1r,
                          const float* __restrict__ W2l, const float* __restrict__ W2r,
                          float* __restrict__ Pg, float* __restrict__ P2g) {
    int i = blockIdx.x * 256 + threadIdx.x;
    if (i < 16384) {
        int k = i >> 7, d = i & 127;
        Pg[i] = (d < 64) ? W1l[d * 128 + k] : W1r[(d - 64) * 128 + k];
    } else if (i < 18432) {
        int j = i - 16384, k = j >> 5, d = j & 31;
        P2g[j] = (d < 16) ? W2l[d * 64 + k] : W2r[(d - 16) * 64 + k];
    }
}

// ---------------- xform1: register-blocked fp32 GEMM w/ reg prefetch ----------------
// C[128 nodes x 128 dims] per block; dims 0..63 -> xl, 64..127 -> xr (h1 buf).
// 4 waves in 2x2; lane owns 8x8 micro-tile; A swizzled by row-group key (q).

#define KC 32
#define LDP 132  // LDS row stride in floats (528 B, 16B-aligned)

__launch_bounds__(256, 4)
__global__ void k_xform1(const float* __restrict__ x, const float* __restrict__ Pg,
                         float* __restrict__ xl, float* __restrict__ xr) {
    __shared__ float At[KC * LDP];  // At[kk][n^swz]  (x tile, transposed, swizzled)
    __shared__ float Bt[KC * LDP];  // Bt[kk][d]      (weights)
    int tid = threadIdx.x;
    int wave = tid >> 6, lane = tid & 63;
    int wr = wave >> 1, wc = wave & 1;
    int li = lane >> 3, lj = lane & 7;
    int tbase = blockIdx.x * 128;
    const float4* x4 = (const float4*)x;
    const float4* Pg4 = (const float4*)Pg;

    float4 av[4], bv[4];
    // prologue: load k0=0 tiles into regs
#pragma unroll
    for (int u = 0; u < 4; ++u) {
        int idx = u * 256 + tid;
        int n = idx >> 3, q = idx & 7;
        int node = min(tbase + n, N_NODES - 1);
        av[u] = x4[node * 32 + q];
        bv[u] = Pg4[idx];  // kk*32+q2 == idx
    }
    float acc[8][8];
#pragma unroll
    for (int i = 0; i < 8; ++i)
#pragma unroll
        for (int j = 0; j < 8; ++j) acc[i][j] = 0.f;

    for (int k0 = 0; k0 < 128; k0 += KC) {
        // write prefetched regs to LDS (A swizzled: col n ^ ((q&7)<<3))
#pragma unroll
        for (int u = 0; u < 4; ++u) {
            int idx = u * 256 + tid;
            int n = idx >> 3, q = idx & 7;
            int ns = n ^ ((q & 7) << 3);
            At[(4 * q + 0) * LDP + ns] = av[u].x;
            At[(4 * q + 1) * LDP + ns] = av[u].y;
            At[(4 * q + 2) * LDP + ns] = av[u].z;
            At[(4 * q + 3) * LDP + ns] = av[u].w;
            int kk = idx >> 5, q2 = idx & 31;
            *(float4*)&Bt[kk * LDP + 4 * q2] = bv[u];
        }
        __syncthreads();
        // issue next K-tile prefetch (consumed after compute)
        if (k0 + KC < 128) {
#pragma unroll
            for (int u = 0; u < 4; ++u) {
                int idx = u * 256 + tid;
                int n = idx >> 3, q = idx & 7;
                int node = min(tbase + n, N_NODES - 1);
                av[u] = x4[node * 32 + ((k0 + KC) >> 2) + q];
                bv[u] = Pg4[(k0 + KC) * 32 + idx];
            }
        }
#pragma unroll 4
        for (int kk = 0; kk < KC; ++kk) {
            float a[8], b[8];
            int lia = (li ^ ((kk >> 2) & 7)) * 8;  // undo A swizzle (key = q = kk>>2)
            *(float4*)&a[0] = *(const float4*)&At[kk * LDP + wr * 64 + lia];
            *(float4*)&a[4] = *(const float4*)&At[kk * LDP + wr * 64 + lia + 4];
            *(float4*)&b[0] = *(const float4*)&Bt[kk * LDP + wc * 64 + lj * 8];
            *(float4*)&b[4] = *(const float4*)&Bt[kk * LDP + wc * 64 + lj * 8 + 4];
#pragma unroll
            for (int i = 0; i < 8; ++i)
#pragma unroll
                for (int j = 0; j < 8; ++j)
                    acc[i][j] = fmaf(a[i], b[j], acc[i][j]);
        }
        __syncthreads();
    }
    // epilogue: wc==0 -> xl, wc==1 -> xr; rows follow the A swizzle of li
    float* outb = wc ? xr : xl;
#pragma unroll
    for (int i = 0; i < 8; ++i) {
        int node = tbase + wr * 64 + li * 8 + i;
        if (node < N_NODES) {
            float4* p = (float4*)(outb + node * 64 + lj * 8);
            p[0] = make_float4(acc[i][0], acc[i][1], acc[i][2], acc[i][3]);
            p[1] = make_float4(acc[i][4], acc[i][5], acc[i][6], acc[i][7]);
        }
    }
}

// ---------------- gather1: h1[n] = relu(h1[n](=xr) + b1 + mean(xl[nbrs])) ----------
// wave per node, lane = dim; 8-wide batches; next-node prefetch. No LDS/barriers.

__launch_bounds__(256)
__global__ void k_gather1(const float* __restrict__ xl, const int* __restrict__ ssrc,
                          const int* __restrict__ offs, const int* __restrict__ deg,
                          const float* __restrict__ b1, float* __restrict__ h1) {
    int tid = blockIdx.x * 256 + threadIdx.x;
    int wid = tid >> 6, lane = tid & 63;
    int nWaves = (gridDim.x * 256) >> 6;
    float bias = b1[lane];

    int node = wid;
    if (node >= N_NODES) return;
    int o = offs[node], dg = deg[node];
    float self = h1[node * 64 + lane];
    while (true) {
        // prefetch next node's metadata + self row (hides under gather)
        int nnode = node + nWaves;
        int no = 0, ndg = 0;
        float nself = 0.f;
        if (nnode < N_NODES) {
            no = offs[nnode];
            ndg = deg[nnode];
            nself = h1[nnode * 64 + lane];
        }
        int os = __builtin_amdgcn_readfirstlane(o);
        int ds = __builtin_amdgcn_readfirstlane(dg);
        float a0 = 0.f, a1 = 0.f, a2 = 0.f, a3 = 0.f;
        float a4 = 0.f, a5 = 0.f, a6 = 0.f, a7 = 0.f;
        int last = ds - 1;
        for (int u = 0; u < ds; u += 8) {
            int n0 = ssrc[os + u];
            int n1 = ssrc[os + min(u + 1, last)];
            int n2 = ssrc[os + min(u + 2, last)];
            int n3 = ssrc[os + min(u + 3, last)];
            int n4 = ssrc[os + min(u + 4, last)];
            int n5 = ssrc[os + min(u + 5, last)];
            int n6 = ssrc[os + min(u + 6, last)];
            int n7 = ssrc[os + min(u + 7, last)];
            float v0 = xl[n0 * 64 + lane];
            float v1 = xl[n1 * 64 + lane];
            float v2 = xl[n2 * 64 + lane];
            float v3 = xl[n3 * 64 + lane];
            float v4 = xl[n4 * 64 + lane];
            float v5 = xl[n5 * 64 + lane];
            float v6 = xl[n6 * 64 + lane];
            float v7 = xl[n7 * 64 + lane];
            a0 += v0;
            a1 = fmaf(v1, (u + 1 < ds) ? 1.f : 0.f, a1);
            a2 = fmaf(v2, (u + 2 < ds) ? 1.f : 0.f, a2);
            a3 = fmaf(v3, (u + 3 < ds) ? 1.f : 0.f, a3);
            a4 = fmaf(v4, (u + 4 < ds) ? 1.f : 0.f, a4);
            a5 = fmaf(v5, (u + 5 < ds) ? 1.f : 0.f, a5);
            a6 = fmaf(v6, (u + 6 < ds) ? 1.f : 0.f, a6);
            a7 = fmaf(v7, (u + 7 < ds) ? 1.f : 0.f, a7);
        }
        float inv = 1.f / (float)max(ds, 1);
        float mean = (((a0 + a1) + (a2 + a3)) + ((a4 + a5) + (a6 + a7))) * inv;
        h1[node * 64 + lane] = fmaxf(self + bias + mean, 0.f);
        if (nnode >= N_NODES) break;
        node = nnode;
        o = no;
        dg = ndg;
        self = nself;
    }
}

// ---------------- xform2: lane = node, scalar weights (8 FMA / s_load float) -------
// h1l[n][0..15] = h1[n] @ W2l.T ; h2pre[n][0..15] = h1[n] @ W2r.T

#define LD2 68  // LDS row stride (floats): bank-rotation, b128 at floor

__launch_bounds__(256)
__global__ void k_xform2(const float* __restrict__ h1, const float* __restrict__ P2g,
                         float* __restrict__ h1l, float* __restrict__ h2pre) {
    __shared__ float S[64 * LD2];  // 17.4 KB
    int tid = threadIdx.x;
    int wave = __builtin_amdgcn_readfirstlane(tid >> 6);
    int lane = tid & 63;
    int tbase = blockIdx.x * 64;
    const float4* h4 = (const float4*)h1;

    // stage 64 rows x 64 floats, coalesced
    for (int idx = tid; idx < 64 * 16; idx += 256) {
        int n = idx >> 4, q = idx & 15;
        int node = min(tbase + n, N_NODES - 1);
        *(float4*)&S[n * LD2 + 4 * q] = h4[node * 16 + q];
    }
    __syncthreads();

    int node = tbase + lane;
    int dbase = wave * 8;  // wave w owns output dims [8w, 8w+8)
    float acc[8] = {0.f, 0.f, 0.f, 0.f, 0.f, 0.f, 0.f, 0.f};
    const float* Sn = S + lane * LD2;
#pragma unroll 4
    for (int k4 = 0; k4 < 16; ++k4) {
        float4 s = *(const float4*)&Sn[4 * k4];
        const float* Wk = P2g + (4 * k4) * 32 + dbase;  // uniform -> s_load
#pragma unroll
        for (int c = 0; c < 4; ++c) {
            float sv = (c == 0) ? s.x : (c == 1) ? s.y : (c == 2) ? s.z : s.w;
            const float* W = Wk + c * 32;
#pragma unroll
            for (int dd = 0; dd < 8; ++dd)
                acc[dd] = fmaf(W[dd], sv, acc[dd]);
        }
    }
    if (node < N_NODES) {
        float4 lo = make_float4(acc[0], acc[1], acc[2], acc[3]);
        float4 hi = make_float4(acc[4], acc[5], acc[6], acc[7]);
        if (wave < 2) {
            float4* p = (float4*)(h1l + node * 16 + wave * 8);
            p[0] = lo;
            p[1] = hi;
        } else {
            float4* p = (float4*)(h2pre + node * 16 + (wave - 2) * 8);
            p[0] = lo;
            p[1] = hi;
        }
    }
}

// ---------------- gather2 + graph pooling ----------------

__launch_bounds__(256)
__global__ void k_g2pool(const float* __restrict__ h1l, const float* __restrict__ h2pre,
                         const int* __restrict__ ssrc, const int* __restrict__ offs,
                         const int* __restrict__ deg, const int* __restrict__ batch,
                         const float* __restrict__ b2,
                         float* __restrict__ gsum, float* __restrict__ gcnt) {
    __shared__ float bins[N_GRAPHS][17];
    int tid = threadIdx.x;
    for (int i = tid; i < N_GRAPHS * 17; i += 256) ((float*)bins)[i] = 0.f;
    __syncthreads();

    int wave = tid >> 6, lane = tid & 63;
    int sub = lane >> 4, d = lane & 15;
    float bias = b2[d];

    int chunk = (N_NODES + gridDim.x - 1) / gridDim.x;
    int cs = blockIdx.x * chunk;
    int ce = min(N_NODES, cs + chunk);

    for (int base = cs + wave * 4; base < ce; base += 16) {
        int node = base + sub;
        bool valid = node < ce;
        int nn = valid ? node : cs;
        int o = offs[nn], dg = deg[nn];
        float a0 = 0.f, a1 = 0.f, a2 = 0.f, a3 = 0.f;
        int last = dg - 1;
        for (int u = 0; u < dg; u += 4) {
            int n0 = ssrc[o + u];
            int n1 = ssrc[o + min(u + 1, last)];
            int n2 = ssrc[o + min(u + 2, last)];
            int n3 = ssrc[o + min(u + 3, last)];
            float v0 = h1l[n0 * 16 + d];
            float v1 = h1l[n1 * 16 + d];
            float v2 = h1l[n2 * 16 + d];
            float v3 = h1l[n3 * 16 + d];
            float m1 = (u + 1 < dg) ? 1.f : 0.f;
            float m2 = (u + 2 < dg) ? 1.f : 0.f;
            float m3 = (u + 3 < dg) ? 1.f : 0.f;
            a0 += v0;
            a1 = fmaf(v1, m1, a1);
            a2 = fmaf(v2, m2, a2);
            a3 = fmaf(v3, m3, a3);
        }
        float inv = 1.f / (float)max(dg, 1);
        float val = h2pre[nn * 16 + d] + bias + ((a0 + a1) + (a2 + a3)) * inv;
        if (valid) {
            int g = batch[nn];
            atomicAdd(&bins[g][d], val);
            if (d == 0) atomicAdd(&bins[g][16], 1.f);
        }
    }
    __syncthreads();
    for (int i = tid; i < N_GRAPHS * 17; i += 256) {
        int g = i / 17, c = i - g * 17;
        float v = bins[g][c];
        if (v != 0.f) {
            if (c < 16) atomicAdd(&gsum[g * 16 + c], v);
            else        atomicAdd(&gcnt[g], v);
        }
    }
}

// ---------------- final: BERT head + graph head, concat ----------------

__global__ void k_final(const float* __restrict__ bert, const float* __restrict__ Wad,
                        const float* __restrict__ bad, const float* __restrict__ Wm,
                        const float* __restrict__ bm, const float* __restrict__ gsum,
                        const float* __restrict__ gcnt, float* __restrict__ out) {
    int g = blockIdx.x;
    int t = threadIdx.x;
    if (t < 64) {
        const float4* br = (const float4*)(bert + g * 768);
        const float4* wr = (const float4*)(Wad + t * 768);
        float acc = bad[t];
#pragma unroll 8
        for (int k = 0; k < 192; ++k) {
            float4 bv = br[k], wv = wr[k];
            acc += bv.x * wv.x + bv.y * wv.y + bv.z * wv.z + bv.w * wv.w;
        }
        out[g * 80 + t] = acc;
    } else if (t < 80) {
        int j = t - 64;
        float ic = 1.f / fmaxf(gcnt[g], 1.f);
        float acc = bm[j];
#pragma unroll
        for (int k = 0; k < 16; ++k) acc += Wm[j * 16 + k] * gsum[g * 16 + k] * ic;
        out[g * 80 + t] = acc;
    }
}

extern "C" void kernel_launch(void* const* d_in, const int* in_sizes, int n_in,
                              void* d_out, int out_size, void* d_ws, size_t ws_size,
                              hipStream_t stream) {
    const float* bert   = (const float*)d_in[0];
    const float* node_x = (const float*)d_in[1];
    const int*   edge   = (const int*)d_in[2];
    const int*   batch  = (const int*)d_in[3];
    const float* Wad    = (const float*)d_in[4];
    const float* bad    = (const float*)d_in[5];
    const float* W1l    = (const float*)d_in[6];
    const float* W1r    = (const float*)d_in[7];
    const float* b1     = (const float*)d_in[8];
    const float* W2l    = (const float*)d_in[9];
    const float* W2r    = (const float*)d_in[10];
    const float* b2     = (const float*)d_in[11];
    const float* Wm     = (const float*)d_in[12];
    const float* bm     = (const float*)d_in[13];
    float* out = (float*)d_out;

    const int* src = edge;
    const int* dst = edge + N_EDGES;

    char* ws = (char*)d_ws;
    int*    deg    = (int*)(ws);                //   400,000 B
    int*    offs   = (int*)(ws + 400000);       //   400,000 B
    int*    cursor = (int*)(ws + 800000);       //   400,000 B
    int*    bsums  = (int*)(ws + 1200000);      //       512 B
    int*    boff   = (int*)(ws + 1200512);      //       512 B
    int*    ssrc   = (int*)(ws + 1201024);      // 2,400,000 B
    float*  xl     = (float*)(ws + 3601024);    // 25,600,000 B  (layer1 projected-l)
    float*  h1     = (float*)(ws + 29201024);   // 25,600,000 B  (xr, then h1 in-place)
    float*  Pg     = (float*)(ws + 54801024);   //    65,536 B  (xform1 weights)
    float*  P2g    = (float*)(ws + 54866560);   //     8,192 B  (xform2 weights)
    float*  gsum   = (float*)(ws + 54874752);   //     4,096 B
    float*  gcnt   = (float*)(ws + 54878848);   //       256 B
    // layer-2 buffers alias dead xl region:
    float*  h1l    = (float*)(ws + 3601024);    //  6,400,000 B
    float*  h2pre  = (float*)(ws + 10001024);   //  6,400,000 B
    // peak ~54.9 MB

    hipMemsetAsync(deg, 0, 400000, stream);
    hipMemsetAsync(gsum, 0, 4096 + 256, stream);

    k_count<<<(N_EDGES + 255) / 256, 256, 0, stream>>>(dst, deg);
    k_scan1<<<(N_NODES + 1023) / 1024, 256, 0, stream>>>(deg, offs, bsums);
    k_scan2<<<1, 128, 0, stream>>>(bsums, boff);
    k_scan3<<<(N_NODES + 255) / 256, 256, 0, stream>>>(offs, boff, cursor);
    k_fill<<<(N_EDGES + 255) / 256, 256, 0, stream>>>(src, dst, cursor, ssrc);
    k_prepack<<<72, 256, 0, stream>>>(W1l, W1r, W2l, W2r, Pg, P2g);

    int nT128 = (N_NODES + 127) / 128;  // 782
    int nT64  = (N_NODES + 63) / 64;    // 1563
    k_xform1<<<nT128, 256, 0, stream>>>(node_x, Pg, xl, h1);
    k_gather1<<<2048, 256, 0, stream>>>(xl, ssrc, offs, deg, b1, h1);
    k_xform2<<<nT64, 256, 0, stream>>>(h1, P2g, h1l, h2pre);
    k_g2pool<<<512, 256, 0, stream>>>(h1l, h2pre, ssrc, offs, deg, batch, b2, gsum, gcnt);
    k_final<<<N_GRAPHS, 128, 0, stream>>>(bert, Wad, bad, Wm, bm, gsum, gcnt, out);
}

// Round 8
// 332.834 us; speedup vs baseline: 1.0046x; 1.0046x over previous
//
#include <hip/hip_runtime.h>

#define N_NODES 100000
#define N_EDGES 600000
#define N_GRAPHS 64

// ---------------- CSR build ----------------

__global__ void k_count(const int* __restrict__ dst, int* __restrict__ deg) {
    int e = blockIdx.x * 256 + threadIdx.x;
    if (e < N_EDGES) atomicAdd(&deg[dst[e]], 1);
}

__global__ void k_scan1(const int* __restrict__ deg, int* __restrict__ offs,
                        int* __restrict__ bsums) {
    __shared__ int s[256];
    int t = threadIdx.x, b = blockIdx.x;
    int base = b * 1024 + t * 4;
    int v0 = (base + 0 < N_NODES) ? deg[base + 0] : 0;
    int v1 = (base + 1 < N_NODES) ? deg[base + 1] : 0;
    int v2 = (base + 2 < N_NODES) ? deg[base + 2] : 0;
    int v3 = (base + 3 < N_NODES) ? deg[base + 3] : 0;
    int tsum = v0 + v1 + v2 + v3;
    s[t] = tsum;
    __syncthreads();
    for (int o = 1; o < 256; o <<= 1) {
        int x = (t >= o) ? s[t - o] : 0;
        __syncthreads();
        s[t] += x;
        __syncthreads();
    }
    int p = s[t] - tsum;
    if (base + 0 < N_NODES) offs[base + 0] = p;
    p += v0;
    if (base + 1 < N_NODES) offs[base + 1] = p;
    p += v1;
    if (base + 2 < N_NODES) offs[base + 2] = p;
    p += v2;
    if (base + 3 < N_NODES) offs[base + 3] = p;
    if (t == 255) bsums[b] = s[255];
}

__global__ void k_scan2(const int* __restrict__ bsums, int* __restrict__ boff) {
    __shared__ int s[128];
    int t = threadIdx.x;
    int nb = (N_NODES + 1023) / 1024;
    int v = (t < nb) ? bsums[t] : 0;
    s[t] = v;
    __syncthreads();
    for (int o = 1; o < 128; o <<= 1) {
        int x = (t >= o) ? s[t - o] : 0;
        __syncthreads();
        s[t] += x;
        __syncthreads();
    }
    boff[t] = s[t] - v;
}

__global__ void k_scan3(int* __restrict__ offs, const int* __restrict__ boff,
                        int* __restrict__ cursor) {
    int i = blockIdx.x * 256 + threadIdx.x;
    if (i < N_NODES) {
        int v = offs[i] + boff[i >> 10];
        offs[i] = v;
        cursor[i] = v;
    }
}

__global__ void k_fill(const int* __restrict__ src, const int* __restrict__ dst,
                       int* __restrict__ cursor, int* __restrict__ ssrc) {
    int e = blockIdx.x * 256 + threadIdx.x;
    if (e < N_EDGES) {
        int d = dst[e];
        int pos = atomicAdd(&cursor[d], 1);
        ssrc[pos] = src[e];
    }
}

// ---------------- weight prepack ----------------
// Pg[k*128 + d]: d<64 -> W1l[d][k], d>=64 -> W1r[d-64][k]   (xform1 B matrix)
// P2g[k*32 + d]: d<16 -> W2l[d][k], d>=16 -> W2r[d-16][k]   (xform2, s_load rows)
__global__ void k_prepack(const float* __restrict__ W1l, const float* __restrict__ W1r,
                          const float* __restrict__ W2l, const float* __restrict__ W2r,
                          float* __restrict__ Pg, float* __restrict__ P2g) {
    int i = blockIdx.x * 256 + threadIdx.x;
    if (i < 16384) {
        int k = i >> 7, d = i & 127;
        Pg[i] = (d < 64) ? W1l[d * 128 + k] : W1r[(d - 64) * 128 + k];
    } else if (i < 18432) {
        int j = i - 16384, k = j >> 5, d = j & 31;
        P2g[j] = (d < 16) ? W2l[d * 64 + k] : W2r[(d - 16) * 64 + k];
    }
}

// ---------------- xform1: 64-node x 128-dim tiles, 2 waves, B from L2 --------------
// A staged in LDS (transposed+swizzled); per kk: 2 ds_read_b128 + 2 global dwordx4
// (8 distinct 32B segments/wave, lane-broadcast) feed 64 FMA. Grid 1563 -> 6 blk/CU.

#define KC1 64
#define LDA 68  // LDS row stride (floats); 272 B, 16B-aligned

__launch_bounds__(128, 4)
__global__ void k_xform1(const float* __restrict__ x, const float* __restrict__ Pg,
                         float* __restrict__ xl, float* __restrict__ xr) {
    __shared__ float At[KC1 * LDA];  // 17.4 KB; At[kk][swz(n)]
    int tid = threadIdx.x;
    int wave = tid >> 6, lane = tid & 63;
    int li = lane >> 3, lj = lane & 7;
    int tbase = blockIdx.x * 64;
    const float4* x4 = (const float4*)x;
    const float4* Pg4 = (const float4*)Pg;

    float acc[8][8];
#pragma unroll
    for (int i = 0; i < 8; ++i)
#pragma unroll
        for (int j = 0; j < 8; ++j) acc[i][j] = 0.f;

    for (int k0 = 0; k0 < 128; k0 += KC1) {
        if (k0) __syncthreads();
        // stage A slice: 64 nodes x 64 k, transposed, float4-col swizzled by q
#pragma unroll
        for (int u = 0; u < 8; ++u) {
            int idx = u * 128 + tid;
            int n = idx >> 4, q = idx & 15;
            int node = min(tbase + n, N_NODES - 1);
            float4 v = x4[node * 32 + (k0 >> 2) + q];
            int col = 4 * ((n >> 2) ^ q) + (n & 3);
            At[(4 * q + 0) * LDA + col] = v.x;
            At[(4 * q + 1) * LDA + col] = v.y;
            At[(4 * q + 2) * LDA + col] = v.z;
            At[(4 * q + 3) * LDA + col] = v.w;
        }
        __syncthreads();
#pragma unroll 4
        for (int kk = 0; kk < KC1; ++kk) {
            int key = kk >> 2;
            float a[8], b[8];
            *(float4*)&a[0] = *(const float4*)&At[kk * LDA + 4 * ((2 * li) ^ key)];
            *(float4*)&a[4] = *(const float4*)&At[kk * LDA + 4 * ((2 * li + 1) ^ key)];
            const float4* bp = Pg4 + (k0 + kk) * 32 + wave * 16 + lj * 2;
            *(float4*)&b[0] = bp[0];
            *(float4*)&b[4] = bp[1];
#pragma unroll
            for (int i = 0; i < 8; ++i)
#pragma unroll
                for (int j = 0; j < 8; ++j)
                    acc[i][j] = fmaf(a[i], b[j], acc[i][j]);
        }
    }
    // epilogue: wave 0 -> xl, wave 1 -> xr
    float* outb = wave ? xr : xl;
#pragma unroll
    for (int i = 0; i < 8; ++i) {
        int node = tbase + li * 8 + i;
        if (node < N_NODES) {
            float4* p = (float4*)(outb + node * 64 + lj * 8);
            p[0] = make_float4(acc[i][0], acc[i][1], acc[i][2], acc[i][3]);
            p[1] = make_float4(acc[i][4], acc[i][5], acc[i][6], acc[i][7]);
        }
    }
}

// ---------------- gather1: h1[n] = relu(h1[n](=xr) + b1 + mean(xl[nbrs])) ----------
// wave per node, lane = dim; 4-wide batches; next-node prefetch. No LDS/barriers.

__launch_bounds__(256)
__global__ void k_gather1(const float* __restrict__ xl, const int* __restrict__ ssrc,
                          const int* __restrict__ offs, const int* __restrict__ deg,
                          const float* __restrict__ b1, float* __restrict__ h1) {
    int tid = blockIdx.x * 256 + threadIdx.x;
    int wid = tid >> 6, lane = tid & 63;
    int nWaves = (gridDim.x * 256) >> 6;
    float bias = b1[lane];

    int node = wid;
    if (node >= N_NODES) return;
    int o = offs[node], dg = deg[node];
    float self = h1[node * 64 + lane];
    while (true) {
        int nnode = node + nWaves;
        int no = 0, ndg = 0;
        float nself = 0.f;
        if (nnode < N_NODES) {
            no = offs[nnode];
            ndg = deg[nnode];
            nself = h1[nnode * 64 + lane];
        }
        int os = __builtin_amdgcn_readfirstlane(o);
        int ds = __builtin_amdgcn_readfirstlane(dg);
        float a0 = 0.f, a1 = 0.f, a2 = 0.f, a3 = 0.f;
        int last = ds - 1;
        for (int u = 0; u < ds; u += 4) {
            int n0 = ssrc[os + u];
            int n1 = ssrc[os + min(u + 1, last)];
            int n2 = ssrc[os + min(u + 2, last)];
            int n3 = ssrc[os + min(u + 3, last)];
            float v0 = xl[n0 * 64 + lane];
            float v1 = xl[n1 * 64 + lane];
            float v2 = xl[n2 * 64 + lane];
            float v3 = xl[n3 * 64 + lane];
            a0 += v0;
            a1 = fmaf(v1, (u + 1 < ds) ? 1.f : 0.f, a1);
            a2 = fmaf(v2, (u + 2 < ds) ? 1.f : 0.f, a2);
            a3 = fmaf(v3, (u + 3 < ds) ? 1.f : 0.f, a3);
        }
        float inv = 1.f / (float)max(ds, 1);
        float mean = ((a0 + a1) + (a2 + a3)) * inv;
        h1[node * 64 + lane] = fmaxf(self + bias + mean, 0.f);
        if (nnode >= N_NODES) break;
        node = nnode;
        o = no;
        dg = ndg;
        self = nself;
    }
}

// ---------------- xform2: lane = node, scalar weights (8 FMA / s_load float) -------

#define LD2 68

__launch_bounds__(256)
__global__ void k_xform2(const float* __restrict__ h1, const float* __restrict__ P2g,
                         float* __restrict__ h1l, float* __restrict__ h2pre) {
    __shared__ float S[64 * LD2];  // 17.4 KB
    int tid = threadIdx.x;
    int wave = __builtin_amdgcn_readfirstlane(tid >> 6);
    int lane = tid & 63;
    int tbase = blockIdx.x * 64;
    const float4* h4 = (const float4*)h1;

    for (int idx = tid; idx < 64 * 16; idx += 256) {
        int n = idx >> 4, q = idx & 15;
        int node = min(tbase + n, N_NODES - 1);
        *(float4*)&S[n * LD2 + 4 * q] = h4[node * 16 + q];
    }
    __syncthreads();

    int node = tbase + lane;
    int dbase = wave * 8;
    float acc[8] = {0.f, 0.f, 0.f, 0.f, 0.f, 0.f, 0.f, 0.f};
    const float* Sn = S + lane * LD2;
#pragma unroll 4
    for (int k4 = 0; k4 < 16; ++k4) {
        float4 s = *(const float4*)&Sn[4 * k4];
        const float* Wk = P2g + (4 * k4) * 32 + dbase;
#pragma unroll
        for (int c = 0; c < 4; ++c) {
            float sv = (c == 0) ? s.x : (c == 1) ? s.y : (c == 2) ? s.z : s.w;
            const float* W = Wk + c * 32;
#pragma unroll
            for (int dd = 0; dd < 8; ++dd)
                acc[dd] = fmaf(W[dd], sv, acc[dd]);
        }
    }
    if (node < N_NODES) {
        float4 lo = make_float4(acc[0], acc[1], acc[2], acc[3]);
        float4 hi = make_float4(acc[4], acc[5], acc[6], acc[7]);
        if (wave < 2) {
            float4* p = (float4*)(h1l + node * 16 + wave * 8);
            p[0] = lo;
            p[1] = hi;
        } else {
            float4* p = (float4*)(h2pre + node * 16 + (wave - 2) * 8);
            p[0] = lo;
            p[1] = hi;
        }
    }
}

// ---------------- gather2 + graph pooling ----------------

__launch_bounds__(256)
__global__ void k_g2pool(const float* __restrict__ h1l, const float* __restrict__ h2pre,
                         const int* __restrict__ ssrc, const int* __restrict__ offs,
                         const int* __restrict__ deg, const int* __restrict__ batch,
                         const float* __restrict__ b2,
                         float* __restrict__ gsum, float* __restrict__ gcnt) {
    __shared__ float bins[N_GRAPHS][17];
    int tid = threadIdx.x;
    for (int i = tid; i < N_GRAPHS * 17; i += 256) ((float*)bins)[i] = 0.f;
    __syncthreads();

    int wave = tid >> 6, lane = tid & 63;
    int sub = lane >> 4, d = lane & 15;
    float bias = b2[d];

    int chunk = (N_NODES + gridDim.x - 1) / gridDim.x;
    int cs = blockIdx.x * chunk;
    int ce = min(N_NODES, cs + chunk);

    for (int base = cs + wave * 4; base < ce; base += 16) {
        int node = base + sub;
        bool valid = node < ce;
        int nn = valid ? node : cs;
        int o = offs[nn], dg = deg[nn];
        float a0 = 0.f, a1 = 0.f, a2 = 0.f, a3 = 0.f;
        int last = dg - 1;
        for (int u = 0; u < dg; u += 4) {
            int n0 = ssrc[o + u];
            int n1 = ssrc[o + min(u + 1, last)];
            int n2 = ssrc[o + min(u + 2, last)];
            int n3 = ssrc[o + min(u + 3, last)];
            float v0 = h1l[n0 * 16 + d];
            float v1 = h1l[n1 * 16 + d];
            float v2 = h1l[n2 * 16 + d];
            float v3 = h1l[n3 * 16 + d];
            float m1 = (u + 1 < dg) ? 1.f : 0.f;
            float m2 = (u + 2 < dg) ? 1.f : 0.f;
            float m3 = (u + 3 < dg) ? 1.f : 0.f;
            a0 += v0;
            a1 = fmaf(v1, m1, a1);
            a2 = fmaf(v2, m2, a2);
            a3 = fmaf(v3, m3, a3);
        }
        float inv = 1.f / (float)max(dg, 1);
        float val = h2pre[nn * 16 + d] + bias + ((a0 + a1) + (a2 + a3)) * inv;
        if (valid) {
            int g = batch[nn];
            atomicAdd(&bins[g][d], val);
            if (d == 0) atomicAdd(&bins[g][16], 1.f);
        }
    }
    __syncthreads();
    for (int i = tid; i < N_GRAPHS * 17; i += 256) {
        int g = i / 17, c = i - g * 17;
        float v = bins[g][c];
        if (v != 0.f) {
            if (c < 16) atomicAdd(&gsum[g * 16 + c], v);
            else        atomicAdd(&gcnt[g], v);
        }
    }
}

// ---------------- final: BERT head + graph head, concat ----------------

__global__ void k_final(const float* __restrict__ bert, const float* __restrict__ Wad,
                        const float* __restrict__ bad, const float* __restrict__ Wm,
                        const float* __restrict__ bm, const float* __restrict__ gsum,
                        const float* __restrict__ gcnt, float* __restrict__ out) {
    int g = blockIdx.x;
    int t = threadIdx.x;
    if (t < 64) {
        const float4* br = (const float4*)(bert + g * 768);
        const float4* wr = (const float4*)(Wad + t * 768);
        float acc = bad[t];
#pragma unroll 8
        for (int k = 0; k < 192; ++k) {
            float4 bv = br[k], wv = wr[k];
            acc += bv.x * wv.x + bv.y * wv.y + bv.z * wv.z + bv.w * wv.w;
        }
        out[g * 80 + t] = acc;
    } else if (t < 80) {
        int j = t - 64;
        float ic = 1.f / fmaxf(gcnt[g], 1.f);
        float acc = bm[j];
#pragma unroll
        for (int k = 0; k < 16; ++k) acc += Wm[j * 16 + k] * gsum[g * 16 + k] * ic;
        out[g * 80 + t] = acc;
    }
}

extern "C" void kernel_launch(void* const* d_in, const int* in_sizes, int n_in,
                              void* d_out, int out_size, void* d_ws, size_t ws_size,
                              hipStream_t stream) {
    const float* bert   = (const float*)d_in[0];
    const float* node_x = (const float*)d_in[1];
    const int*   edge   = (const int*)d_in[2];
    const int*   batch  = (const int*)d_in[3];
    const float* Wad    = (const float*)d_in[4];
    const float* bad    = (const float*)d_in[5];
    const float* W1l    = (const float*)d_in[6];
    const float* W1r    = (const float*)d_in[7];
    const float* b1     = (const float*)d_in[8];
    const float* W2l    = (const float*)d_in[9];
    const float* W2r    = (const float*)d_in[10];
    const float* b2     = (const float*)d_in[11];
    const float* Wm     = (const float*)d_in[12];
    const float* bm     = (const float*)d_in[13];
    float* out = (float*)d_out;

    const int* src = edge;
    const int* dst = edge + N_EDGES;

    char* ws = (char*)d_ws;
    int*    deg    = (int*)(ws);                //   400,000 B
    int*    offs   = (int*)(ws + 400000);       //   400,000 B
    int*    cursor = (int*)(ws + 800000);       //   400,000 B
    int*    bsums  = (int*)(ws + 1200000);      //       512 B
    int*    boff   = (int*)(ws + 1200512);      //       512 B
    int*    ssrc   = (int*)(ws + 1201024);      // 2,400,000 B
    float*  xl     = (float*)(ws + 3601024);    // 25,600,000 B
    float*  h1     = (float*)(ws + 29201024);   // 25,600,000 B  (xr, then h1 in-place)
    float*  Pg     = (float*)(ws + 54801024);   //    65,536 B
    float*  P2g    = (float*)(ws + 54866560);   //     8,192 B
    float*  gsum   = (float*)(ws + 54874752);   //     4,096 B
    float*  gcnt   = (float*)(ws + 54878848);   //       256 B
    // layer-2 buffers alias dead xl region:
    float*  h1l    = (float*)(ws + 3601024);    //  6,400,000 B
    float*  h2pre  = (float*)(ws + 10001024);   //  6,400,000 B
    // peak ~54.9 MB

    hipMemsetAsync(deg, 0, 400000, stream);
    hipMemsetAsync(gsum, 0, 4096 + 256, stream);

    k_count<<<(N_EDGES + 255) / 256, 256, 0, stream>>>(dst, deg);
    k_scan1<<<(N_NODES + 1023) / 1024, 256, 0, stream>>>(deg, offs, bsums);
    k_scan2<<<1, 128, 0, stream>>>(bsums, boff);
    k_scan3<<<(N_NODES + 255) / 256, 256, 0, stream>>>(offs, boff, cursor);
    k_fill<<<(N_EDGES + 255) / 256, 256, 0, stream>>>(src, dst, cursor, ssrc);
    k_prepack<<<72, 256, 0, stream>>>(W1l, W1r, W2l, W2r, Pg, P2g);

    int nT64 = (N_NODES + 63) / 64;  // 1563
    k_xform1<<<nT64, 128, 0, stream>>>(node_x, Pg, xl, h1);
    k_gather1<<<2048, 256, 0, stream>>>(xl, ssrc, offs, deg, b1, h1);
    k_xform2<<<nT64, 256, 0, stream>>>(h1, P2g, h1l, h2pre);
    k_g2pool<<<512, 256, 0, stream>>>(h1l, h2pre, ssrc, offs, deg, batch, b2, gsum, gcnt);
    k_final<<<N_GRAPHS, 128, 0, stream>>>(bert, Wad, bad, Wm, bm, gsum, gcnt, out);
}